// Round 4
// baseline (45.062 us; speedup 1.0000x reference)
//
#include <hip/hip_runtime.h>
#include <math.h>

#define NW 11
#define NL 8
#define NPIX 1024
#define TPB 256

typedef float f2 __attribute__((ext_vector_type(2)));
typedef float f4 __attribute__((ext_vector_type(4)));

struct PermTab { int fe[NL][8]; int d[NL][8]; };

// Composed CNOT-ring permutation (validated rounds 1-3): ascending q,
// m ^= ((m>>pc)&1)<<pt, pc=10-q, pt=10-((q+r)%11).
__host__ __device__ inline int fmap_h(int m, int r) {
    for (int q = 0; q < NW; ++q) {
        int pc = 10 - q;
        int qq = q + r; if (qq >= NW) qq -= NW;
        int pt = 10 - qq;
        m ^= ((m >> pc) & 1) << pt;
    }
    return m;
}

// GF(2)-linear LDS swizzle (f2-element granularity). Bits [3:1] ^= bits
// [5:3], bit3 ^= bit6: spreads t[3:0] into the bank residue for every
// structured round; preserves bit0 (b128 pairing) and bits >= 7.
__host__ __device__ constexpr int SW(int e) {
    return e ^ (((e >> 3) & 7) << 1) ^ (((e >> 6) & 1) << 3);
}

// One 2x2 complex gate on 4 register pairs (pairing mask B) in packed-f32.
// g: 8 f2 coefs {(u00r,u00r),(-u00i,u00i),(u01r,u01r),(-u01i,u01i),
//                (u10r,u10r),(-u10i,u10i),(u11r,u11r),(-u11i,u11i)}.
template<int B>
__device__ __forceinline__ void gate8(f2 (&v)[8], const f2* __restrict__ g) {
    f2 c0 = g[0], c1 = g[1], c2 = g[2], c3 = g[3];
    f2 c4 = g[4], c5 = g[5], c6 = g[6], c7 = g[7];
    #pragma unroll
    for (int s = 0; s < 8; ++s) {
        if (s & B) continue;
        f2 v0 = v[s], v1 = v[s | B];
        f2 w0 = v0.yx, w1 = v1.yx;
        f2 o0 = __builtin_elementwise_fma(c3, w1,
                 __builtin_elementwise_fma(c2, v1,
                  __builtin_elementwise_fma(c1, w0, c0 * v0)));
        f2 o1 = __builtin_elementwise_fma(c7, w1,
                 __builtin_elementwise_fma(c6, v1,
                  __builtin_elementwise_fma(c5, w0, c4 * v0)));
        v[s] = o0; v[s | B] = o1;
    }
}

// ---- kernel 1: 88 Rot gate matrices -> d_ws (weights-only) ----
__global__ void gates_kernel(const float* __restrict__ weights, f2* __restrict__ gw) {
    int t = threadIdx.x;
    if (t < NL * NW) {
        const float* w = weights + t * 3;
        const float PI = 3.14159265358979323846f;
        float phi   = PI * tanhf(w[0]);
        float theta = PI * tanhf(w[1]);
        float omega = PI * tanhf(w[2]);
        float ct = cosf(0.5f * theta), st = sinf(0.5f * theta);
        float a  = 0.5f * (phi + omega), bb = 0.5f * (phi - omega);
        float ca = cosf(a), sa = sinf(a), cb = cosf(bb), sb = sinf(bb);
        float u00r =  ca * ct, u00i = -sa * ct;
        float u01r = -cb * st, u01i = -sb * st;
        float u10r =  cb * st, u10i = -sb * st;
        float u11r =  ca * ct, u11i =  sa * ct;
        f2* g = gw + t * 8;
        g[0] = (f2){u00r, u00r}; g[1] = (f2){-u00i, u00i};
        g[2] = (f2){u01r, u01r}; g[3] = (f2){-u01i, u01i};
        g[4] = (f2){u10r, u10r}; g[5] = (f2){-u10i, u10i};
        g[6] = (f2){u11r, u11r}; g[7] = (f2){-u11i, u11i};
    }
}

// ---- kernel 2: one 256-thread block per batch element, 8 f2/thread ----
__global__ __launch_bounds__(TPB) void pqc_kernel(
    const float* __restrict__ image, const float* __restrict__ label,
    const f2* __restrict__ gw, float* __restrict__ out, PermTab pt)
{
    __shared__ __align__(16) f2 sS[2048];
    __shared__ float sRed[4];

    const int b = blockIdx.x, t = threadIdx.x;

    // image: 4 floats/thread
    const f4 x = ((const f4*)(image + (size_t)b * NPIX))[t];
    float ss = x.x * x.x + x.y * x.y + x.z * x.z + x.w * x.w;
    #pragma unroll
    for (int off = 32; off >= 1; off >>= 1) ss += __shfl_down(ss, off);
    if ((t & 63) == 0) sRed[t >> 6] = ss;
    __syncthreads();
    const float inv = 1.0f / sqrtf(sRed[0] + sRed[1] + sRed[2] + sRed[3]);

    const float lab = label[b];
    const float cl = cosf(0.5f * lab), sl = sinf(0.5f * lab);

    // init + RX(wire10): thread t owns amps 8t..8t+7 (= layer-0 R0 fragment)
    f2 v[8];
    {
        float ps[4] = {x.x, x.y, x.z, x.w};
        #pragma unroll
        for (int m = 0; m < 4; ++m) {
            float p = ps[m] * inv;
            v[2 * m]     = (f2){cl * p, 0.f};
            v[2 * m + 1] = (f2){0.f, -sl * p};
        }
    }

    const int swb0 = SW(t << 3);                              // R0/output base
    const int swb1 = SW((t & 7) | ((t >> 3) << 6));           // R1 base
    const int swb2 = SW((t & 63) | ((t >> 6) << 9));          // R2 base
    const int swb3 = SW(t << 1);                              // R3 base

    for (int l = 0; l < NL; ++l) {
        const f2* G = gw + (size_t)l * NW * 8;

        // ---- R0: amp bits {0,1,2} = wires 10,9,8 (b128) ----
        if (l) {
            #pragma unroll
            for (int k = 0; k < 4; ++k) {
                f4 w = *(const f4*)&sS[swb0 ^ SW(2 * k)];
                v[2 * k] = w.xy; v[2 * k + 1] = w.zw;
            }
        }
        gate8<1>(v, G + 10 * 8);
        gate8<2>(v, G +  9 * 8);
        gate8<4>(v, G +  8 * 8);
        #pragma unroll
        for (int k = 0; k < 4; ++k) {
            f4 w; w.xy = v[2 * k]; w.zw = v[2 * k + 1];
            *(f4*)&sS[swb0 ^ SW(2 * k)] = w;
        }
        __syncthreads();

        // ---- R1: amp bits {3,4,5} = wires 7,6,5 (b64) ----
        {
            #pragma unroll
            for (int s = 0; s < 8; ++s) v[s] = sS[swb1 ^ SW(s << 3)];
            gate8<1>(v, G + 7 * 8);
            gate8<2>(v, G + 6 * 8);
            gate8<4>(v, G + 5 * 8);
            #pragma unroll
            for (int s = 0; s < 8; ++s) sS[swb1 ^ SW(s << 3)] = v[s];
        }
        __syncthreads();

        // ---- R2: amp bits {6,7,8} = wires 4,3,2 (b64) ----
        {
            #pragma unroll
            for (int s = 0; s < 8; ++s) v[s] = sS[swb2 ^ SW(s << 6)];
            gate8<1>(v, G + 4 * 8);
            gate8<2>(v, G + 3 * 8);
            gate8<4>(v, G + 2 * 8);
            #pragma unroll
            for (int s = 0; s < 8; ++s) sS[swb2 ^ SW(s << 6)] = v[s];
        }
        __syncthreads();

        // ---- R3: amp bits {0,9,10}; gates wires 1,0; CNOT perm on store ----
        {
            #pragma unroll
            for (int k = 0; k < 4; ++k) {
                f4 w = *(const f4*)&sS[swb3 ^ ((k & 1) << 9) ^ ((k >> 1) << 10)];
                v[2 * k] = w.xy; v[2 * k + 1] = w.zw;
            }
            gate8<2>(v, G + 1 * 8);   // amp bit 9  = wire 1
            gate8<4>(v, G + 0 * 8);   // amp bit 10 = wire 0
            // store amp e at SW(F_l(e)); F_l GF(2)-linear, tables in kernarg
            int msw = 0;
            #pragma unroll
            for (int k2 = 0; k2 < 8; ++k2)
                msw ^= ((t >> k2) & 1) ? pt.fe[l][k2] : 0;
            #pragma unroll
            for (int s = 0; s < 8; ++s) sS[msw ^ pt.d[l][s]] = v[s];
        }
        __syncthreads();
    }

    // ---- output: |amp[8t+2k]|^2 * NPIX -> out[b*1024 + 4t + k], f4 store ----
    {
        f4 o;
        #pragma unroll
        for (int k = 0; k < 4; ++k) {
            f2 a = sS[swb0 ^ SW(2 * k)];
            ((float*)&o)[k] = (a.x * a.x + a.y * a.y) * (float)NPIX;
        }
        ((f4*)(out + (size_t)b * NPIX))[t] = o;
    }
}

extern "C" void kernel_launch(void* const* d_in, const int* in_sizes, int n_in,
                              void* d_out, int out_size, void* d_ws, size_t ws_size,
                              hipStream_t stream) {
    const float* image   = (const float*)d_in[0];
    const float* label   = (const float*)d_in[1];
    const float* weights = (const float*)d_in[2];
    float* out = (float*)d_out;
    f2* gw = (f2*)d_ws;   // 88 gates * 8 f2 = 5632 bytes

    // host-side permutation tables (pure, deterministic)
    PermTab pt;
    for (int l = 0; l < NL; ++l) {
        int r = l + 1;
        for (int k = 0; k < 8; ++k)
            pt.fe[l][k] = SW(fmap_h(1 << (k + 1), r));   // t bit k -> amp bit k+1
        for (int s = 0; s < 8; ++s) {
            int m = 0;
            if (s & 1) m ^= fmap_h(1,       r);          // s bit0 -> amp bit 0
            if (s & 2) m ^= fmap_h(1 << 9,  r);          // s bit1 -> amp bit 9
            if (s & 4) m ^= fmap_h(1 << 10, r);          // s bit2 -> amp bit 10
            pt.d[l][s] = SW(m);
        }
    }

    int batch = in_sizes[1];  // 1024
    gates_kernel<<<1, 128, 0, stream>>>(weights, gw);
    pqc_kernel<<<batch, TPB, 0, stream>>>(image, label, gw, out, pt);
}